// Round 3
// baseline (464.605 us; speedup 1.0000x reference)
//
#include <hip/hip_runtime.h>
#include <hip/hip_bf16.h>
#include <math.h>

#define OUT_H 7
#define OUT_W 35
#define NBINS (OUT_H * OUT_W)   // 245
#define NCH   256
#define NROI  512

// NHWC f16 workspace site offsets per level (site = 256 ch = 512 B):
//   l0: 0, l1: 131072, l2: 163840, l3: 172032  (174080 sites = 89.1 MB)

typedef _Float16 h2_t __attribute__((ext_vector_type(2)));
typedef float    f4_t __attribute__((ext_vector_type(4)));  // nontemporal-loadable

static __device__ __forceinline__ h2_t as_h2(unsigned u) {
  return __builtin_bit_cast(h2_t, u);
}
static __device__ __forceinline__ unsigned h2_bits(h2_t v) {
  return __builtin_bit_cast(unsigned, v);
}
static __device__ __forceinline__ unsigned pkrtz_bits(float a, float b) {
  return __builtin_bit_cast(unsigned, __builtin_amdgcn_cvt_pkrtz(a, b));
}
// pack two RTN-rounded halves into one dword (lo = a, hi = b)
static __device__ __forceinline__ unsigned pk_rtn(float a, float b) {
  _Float16 ha = (_Float16)a, hb = (_Float16)b;
  return (unsigned)__builtin_bit_cast(unsigned short, ha) |
         ((unsigned)__builtin_bit_cast(unsigned short, hb) << 16);
}

// ---------------------------------------------------------------------------
// Kernel 1: NCHW fp32 -> NHWC f16, tile = 64 ch x 64 hw.
// LDS 64*65*4 = 16.6 KB -> 8 blocks/CU (wave-capped occupancy).
// Reads: nontemporal float4 (source read exactly once; keep it out of L3 so
// the f16 ws being produced stays resident for kernel 2).
// LDS pitch 65 (odd): both phases <=2-way on banks (free).
// ---------------------------------------------------------------------------
__global__ __launch_bounds__(256, 8) void transpose_all(
    const float* __restrict__ f0, const float* __restrict__ f1,
    const float* __restrict__ f2, const float* __restrict__ f3,
    ushort* __restrict__ ws)
{
  __shared__ float tile[64 * 65];  // 16.64 KB

  const int t = blockIdx.x;
  int l, rel;
  if      (t < 8192)  { l = 0; rel = t; }
  else if (t < 10240) { l = 1; rel = t - 8192; }
  else if (t < 10752) { l = 2; rel = t - 10240; }
  else                { l = 3; rel = t - 10752; }

  const int HWl  = 65536 >> (2 * l);
  const int lg   = 10 - 2 * l;           // log2(HWl/64)
  const int hwT  = rel & ((1 << lg) - 1);
  const int rest = rel >> lg;
  const int cT   = rest & 3;
  const int b    = rest >> 2;
  const float* fsrc = (l == 0) ? f0 : (l == 1) ? f1 : (l == 2) ? f2 : f3;
  const int pixoff  = (l == 0) ? 0 : (l == 1) ? 131072 : (l == 2) ? 163840 : 172032;
  const int hw0 = hwT << 6;
  const int c0  = cT << 6;

  // ---- read: float4, 4 rows x 256 B contiguous per wave-instr ----
  const int hwq = threadIdx.x & 15;
  const int r0  = threadIdx.x >> 4;  // 0..15
#pragma unroll
  for (int i = 0; i < 4; ++i) {
    const int r = r0 + 16 * i;
    const f4_t v = __builtin_nontemporal_load(
        (const f4_t*)(fsrc + ((size_t)(b * NCH + c0 + r)) * HWl + hw0 + 4 * hwq));
    float* tp = &tile[r * 65 + 4 * hwq];
    tp[0] = v.x; tp[1] = v.y; tp[2] = v.z; tp[3] = v.w;
  }
  __syncthreads();

  // ---- write: transposed reads (2-way, free) + pkrtz + uint2 stores ----
  const int cq  = threadIdx.x & 15;   // channel quad
  const int hwl = threadIdx.x >> 4;   // 0..15
  ushort* wp = ws + ((size_t)(pixoff + b * HWl + hw0)) * NCH + c0 + cq * 4;
#pragma unroll
  for (int j = 0; j < 4; ++j) {
    const int hw = hwl + 16 * j;
    const float a0 = tile[(4 * cq + 0) * 65 + hw];
    const float a1 = tile[(4 * cq + 1) * 65 + hw];
    const float a2 = tile[(4 * cq + 2) * 65 + hw];
    const float a3 = tile[(4 * cq + 3) * 65 + hw];
    *(uint2*)(wp + (size_t)hw * NCH) =
        make_uint2(pkrtz_bits(a0, a1), pkrtz_bits(a2, a3));
  }
}

// ---------------------------------------------------------------------------
// Kernel 2: rotated RoIAlign gather + mean + max over levels, f16 packed math.
// Block = (roi n, oh, channel-half). Lane = 2 channels. Grid 7168, swizzled so
// all 14 blocks of roi n share blockIdx%8 (same XCD) for L2 locality.
// LDS: desc 8960 + s_out 9240 = 18.2 KB -> 8 blocks/CU (32 waves).
// Hot loop: wave-uniform tap offset -> readfirstlane -> SGPR base + imm
// offsets (addr math on SALU); weight splats via shufflevector -> op_sel on
// v_pk_fma_f16 (zero-instr broadcast). 5 VALU per 4 taps.
// ---------------------------------------------------------------------------
__global__ __launch_bounds__(256, 8) void roi_align_rotated_max(
    const ushort* __restrict__ ft,   // NHWC f16 (bits), all levels
    const float* __restrict__ rois,  // [512][6]
    float* __restrict__ out)         // [512][256][7][35]
{
  __shared__ uint4    s_desc[OUT_W * 16];  // 8960 B: {byte_off, w01, w23, pad}
  __shared__ unsigned s_out[OUT_W * 66];   // 9240 B: f16 pairs, pitch 66 uints

  const int g    = blockIdx.x;
  const int slot = g & 7;
  const int rest = g >> 3;
  const int hc   = rest % 14;
  const int oh   = hc % 7;
  const int ch2  = hc / 7;                 // channel half (0: ch 0-127, 1: 128-255)
  const int n    = slot + 8 * (rest / 14);

  const float* R = rois + n * 6;
  const int b = (int)R[0];
  const float ct = (float)cos((double)R[5]);
  const float st = (float)sin((double)R[5]);

  // ---- Phase 1: 560 sample descriptors (independent of ch2) ----
  for (int j = threadIdx.x; j < OUT_W * 16; j += 256) {
    const int ow = j >> 4;
    const int ls = j & 15;
    const int l  = ls >> 2;
    const int s  = ls & 3;
    const int sy = s >> 1, sx = s & 1;

    const int   Hl     = 256 >> l;
    const float scale  = 0.25f / (float)(1 << l);
    const int   pixoff = (l == 0) ? 0 : (l == 1) ? 131072 : (l == 2) ? 163840 : 172032;

    // mirror reference f32 op order exactly; no FMA contraction
    const float cx = __fmul_rn(R[1], scale);
    const float cy = __fmul_rn(R[2], scale);
    const float w  = fmaxf(__fmul_rn(R[3], scale), 1.0f);
    const float h  = fmaxf(__fmul_rn(R[4], scale), 1.0f);
    const float bin_h = __fdiv_rn(h, (float)OUT_H);
    const float bin_w = __fdiv_rn(w, (float)OUT_W);
    const float gy = (float)oh + (sy ? 0.75f : 0.25f);
    const float gx = (float)ow + (sx ? 0.75f : 0.25f);
    const float yy = __fadd_rn(__fmul_rn(-h, 0.5f), __fmul_rn(gy, bin_h));
    const float xx = __fadd_rn(__fmul_rn(-w, 0.5f), __fmul_rn(gx, bin_w));
    const float x = __fadd_rn(__fsub_rn(__fmul_rn(xx, ct), __fmul_rn(yy, st)), cx);
    const float y = __fadd_rn(__fadd_rn(__fmul_rn(xx, st), __fmul_rn(yy, ct)), cy);

    const bool valid = (y >= -1.0f) && (y <= (float)Hl) &&
                       (x >= -1.0f) && (x <= (float)Hl);
    float yc = fminf(fmaxf(y, 0.0f), (float)(Hl - 1));
    float xc = fminf(fmaxf(x, 0.0f), (float)(Hl - 1));
    int y0 = (int)floorf(yc);
    int x0 = (int)floorf(xc);
    float ly = yc - (float)y0;
    float lx = xc - (float)x0;
    if (y0 >= Hl - 1) { y0 = Hl - 2; ly = 1.0f; }
    if (x0 >= Hl - 1) { x0 = Hl - 2; lx = 1.0f; }
    const float hy = 1.0f - ly, hx = 1.0f - lx;
    const float sc = valid ? 0.25f : 0.0f;  // fold 1/ns^2 sample mean

    s_desc[j] = make_uint4(
        (unsigned)((pixoff + (b * Hl + y0) * Hl + x0) * (NCH * 2)),  // byte off
        pk_rtn(sc * hy * hx, sc * hy * lx),
        pk_rtn(sc * ly * hx, sc * ly * lx), 0u);
  }
  __syncthreads();

  const int wv     = threadIdx.x >> 6;
  const int lane   = threadIdx.x & 63;
  const int volane = ch2 * 256 + lane * 4;   // per-lane byte offset in a site

  for (int ow = wv; ow < OUT_W; ow += 4) {
    h2_t m;
#pragma unroll
    for (int l = 0; l < 4; ++l) {
      const int rowb = 131072 >> l;  // (256>>l)*512 bytes
      h2_t a = {(_Float16)0, (_Float16)0};
#pragma unroll
      for (int s = 0; s < 4; ++s) {
        const uint4 q = s_desc[ow * 16 + l * 4 + s];
        // q.x is wave-uniform (uniform LDS read) -> pin to SGPR so the four
        // corner loads use the SGPR-base + VGPR-offset + imm form.
        const unsigned off = __builtin_amdgcn_readfirstlane(q.x);
        const char* p0 = (const char*)ft + off;          // SGPR base (y0 row)
        const char* p1 = p0 + rowb;                      // SGPR base (y1 row)
        const unsigned A = *(const unsigned*)(p0 + volane);        // (y0,x0)
        const unsigned B = *(const unsigned*)(p0 + volane + 512);  // (y0,x1)
        const unsigned C = *(const unsigned*)(p1 + volane);        // (y1,x0)
        const unsigned D = *(const unsigned*)(p1 + volane + 512);  // (y1,x1)
        const h2_t w01 = as_h2(q.y), w23 = as_h2(q.z);
        a = __builtin_shufflevector(w01, w01, 0, 0) * as_h2(A) + a;
        a = __builtin_shufflevector(w01, w01, 1, 1) * as_h2(B) + a;
        a = __builtin_shufflevector(w23, w23, 0, 0) * as_h2(C) + a;
        a = __builtin_shufflevector(w23, w23, 1, 1) * as_h2(D) + a;
      }
      if (l == 0) m = a;
      else        m = __builtin_elementwise_max(m, a);
    }
    s_out[ow * 66 + lane] = h2_bits(m);  // 2-way banks, free
  }
  __syncthreads();

  // ---- near-coalesced transposed write-out (f16 -> f32) ----
  // Plain stores: co-resident oh-blocks of the same roi merge partial 64 B
  // lines in L2 (NT stores here cost +31 MB write amplification, measured).
  const size_t outbase = (size_t)n * NCH * NBINS + (size_t)ch2 * 128 * NBINS +
                         (size_t)oh * OUT_W;
  const _Float16* sh = (const _Float16*)s_out;
#pragma unroll
  for (int j = 0; j < 18; ++j) {
    const int idx = threadIdx.x + j * 256;  // 0..4607, guard 4480
    if (idx < 128 * OUT_W) {
      const int cc = idx / OUT_W;           // magic-mul const div
      const int ww = idx - cc * OUT_W;
      out[outbase + (size_t)cc * NBINS + ww] = (float)sh[ww * 132 + cc];
    }
  }
}

// ---------------------------------------------------------------------------
extern "C" void kernel_launch(void* const* d_in, const int* in_sizes, int n_in,
                              void* d_out, int out_size, void* d_ws, size_t ws_size,
                              hipStream_t stream) {
  const float* f0 = (const float*)d_in[0];
  const float* f1 = (const float*)d_in[1];
  const float* f2 = (const float*)d_in[2];
  const float* f3 = (const float*)d_in[3];
  const float* rois = (const float*)d_in[4];
  ushort* ws = (ushort*)d_ws;
  float* out = (float*)d_out;

  transpose_all<<<10880, 256, 0, stream>>>(f0, f1, f2, f3, ws);
  roi_align_rotated_max<<<7168, 256, 0, stream>>>(ws, rois, out);
}

// Round 4
// 377.326 us; speedup vs baseline: 1.2313x; 1.2313x over previous
//
#include <hip/hip_runtime.h>
#include <hip/hip_bf16.h>
#include <math.h>

#define OUT_H 7
#define OUT_W 35
#define NBINS (OUT_H * OUT_W)   // 245
#define NCH   256
#define NROI  512

// NHWC f16 workspace site offsets per level (site = 256 ch = 512 B):
//   l0: 0, l1: 131072, l2: 163840, l3: 172032  (174080 sites = 89.1 MB)

typedef _Float16 h2_t __attribute__((ext_vector_type(2)));
typedef float    f4_t __attribute__((ext_vector_type(4)));  // nontemporal-loadable

static __device__ __forceinline__ h2_t as_h2(unsigned u) {
  return __builtin_bit_cast(h2_t, u);
}
static __device__ __forceinline__ unsigned h2_bits(h2_t v) {
  return __builtin_bit_cast(unsigned, v);
}
static __device__ __forceinline__ unsigned pkrtz_bits(float a, float b) {
  return __builtin_bit_cast(unsigned, __builtin_amdgcn_cvt_pkrtz(a, b));
}
// pack two RTN-rounded halves into one dword (lo = a, hi = b)
static __device__ __forceinline__ unsigned pk_rtn(float a, float b) {
  _Float16 ha = (_Float16)a, hb = (_Float16)b;
  return (unsigned)__builtin_bit_cast(unsigned short, ha) |
         ((unsigned)__builtin_bit_cast(unsigned short, hb) << 16);
}

// ---------------------------------------------------------------------------
// Kernel 1: NCHW fp32 -> NHWC f16, tile = 64 ch x 64 hw.
// LDS 64*65*4 = 16.6 KB -> 8 blocks/CU. LDS pitch 65 (odd): <=2-way banks.
// (Counters for this kernel have never surfaced; if kernel 2 drops below it,
// it will appear in top-5 next round and get attacked with data.)
// ---------------------------------------------------------------------------
__global__ __launch_bounds__(256, 8) void transpose_all(
    const float* __restrict__ f0, const float* __restrict__ f1,
    const float* __restrict__ f2, const float* __restrict__ f3,
    ushort* __restrict__ ws)
{
  __shared__ float tile[64 * 65];  // 16.64 KB

  const int t = blockIdx.x;
  int l, rel;
  if      (t < 8192)  { l = 0; rel = t; }
  else if (t < 10240) { l = 1; rel = t - 8192; }
  else if (t < 10752) { l = 2; rel = t - 10240; }
  else                { l = 3; rel = t - 10752; }

  const int HWl  = 65536 >> (2 * l);
  const int lg   = 10 - 2 * l;           // log2(HWl/64)
  const int hwT  = rel & ((1 << lg) - 1);
  const int rest = rel >> lg;
  const int cT   = rest & 3;
  const int b    = rest >> 2;
  const float* fsrc = (l == 0) ? f0 : (l == 1) ? f1 : (l == 2) ? f2 : f3;
  const int pixoff  = (l == 0) ? 0 : (l == 1) ? 131072 : (l == 2) ? 163840 : 172032;
  const int hw0 = hwT << 6;
  const int c0  = cT << 6;

  // ---- read: float4, 4 rows x 256 B contiguous per wave-instr ----
  const int hwq = threadIdx.x & 15;
  const int r0  = threadIdx.x >> 4;  // 0..15
#pragma unroll
  for (int i = 0; i < 4; ++i) {
    const int r = r0 + 16 * i;
    const f4_t v = __builtin_nontemporal_load(
        (const f4_t*)(fsrc + ((size_t)(b * NCH + c0 + r)) * HWl + hw0 + 4 * hwq));
    float* tp = &tile[r * 65 + 4 * hwq];
    tp[0] = v.x; tp[1] = v.y; tp[2] = v.z; tp[3] = v.w;
  }
  __syncthreads();

  // ---- write: transposed reads (2-way, free) + pkrtz + uint2 stores ----
  const int cq  = threadIdx.x & 15;   // channel quad
  const int hwl = threadIdx.x >> 4;   // 0..15
  ushort* wp = ws + ((size_t)(pixoff + b * HWl + hw0)) * NCH + c0 + cq * 4;
#pragma unroll
  for (int j = 0; j < 4; ++j) {
    const int hw = hwl + 16 * j;
    const float a0 = tile[(4 * cq + 0) * 65 + hw];
    const float a1 = tile[(4 * cq + 1) * 65 + hw];
    const float a2 = tile[(4 * cq + 2) * 65 + hw];
    const float a3 = tile[(4 * cq + 3) * 65 + hw];
    *(uint2*)(wp + (size_t)hw * NCH) =
        make_uint2(pkrtz_bits(a0, a1), pkrtz_bits(a2, a3));
  }
}

// ---------------------------------------------------------------------------
// Kernel 2: rotated RoIAlign gather + mean + max over levels, f16 packed math.
// Block = (roi n, oh, channel-half). Lane = 2 channels. Grid 7168, swizzled so
// all 14 blocks of roi n share blockIdx%8 (same XCD) for L2 locality.
// LDS: desc 8960 + s_out 9240 = 18.2 KB -> 8 blocks/CU (32 waves).
// Hot loop: per l-level, batch 4 descriptor reads + 16 tap loads into regs
// (16 VMEM in flight per wave), THEN the 16 pk_fma in the reference order.
// Latency-bound fix: MLP, not instruction count. No readfirstlane (its
// per-group lgkmcnt(0) + SALU chain serialized the loop; measured +16 us).
// ---------------------------------------------------------------------------
__global__ __launch_bounds__(256, 8) void roi_align_rotated_max(
    const ushort* __restrict__ ft,   // NHWC f16 (bits), all levels
    const float* __restrict__ rois,  // [512][6]
    float* __restrict__ out)         // [512][256][7][35]
{
  __shared__ uint4    s_desc[OUT_W * 16];  // 8960 B: {byte_off, w01, w23, pad}
  __shared__ unsigned s_out[OUT_W * 66];   // 9240 B: f16 pairs, pitch 66 uints

  const int g    = blockIdx.x;
  const int slot = g & 7;
  const int rest = g >> 3;
  const int hc   = rest % 14;
  const int oh   = hc % 7;
  const int ch2  = hc / 7;                 // channel half (0: ch 0-127, 1: 128-255)
  const int n    = slot + 8 * (rest / 14);

  const float* R = rois + n * 6;
  const int b = (int)R[0];
  const float ct = (float)cos((double)R[5]);
  const float st = (float)sin((double)R[5]);

  // ---- Phase 1: 560 sample descriptors (independent of ch2) ----
  for (int j = threadIdx.x; j < OUT_W * 16; j += 256) {
    const int ow = j >> 4;
    const int ls = j & 15;
    const int l  = ls >> 2;
    const int s  = ls & 3;
    const int sy = s >> 1, sx = s & 1;

    const int   Hl     = 256 >> l;
    const float scale  = 0.25f / (float)(1 << l);
    const int   pixoff = (l == 0) ? 0 : (l == 1) ? 131072 : (l == 2) ? 163840 : 172032;

    // mirror reference f32 op order exactly; no FMA contraction
    const float cx = __fmul_rn(R[1], scale);
    const float cy = __fmul_rn(R[2], scale);
    const float w  = fmaxf(__fmul_rn(R[3], scale), 1.0f);
    const float h  = fmaxf(__fmul_rn(R[4], scale), 1.0f);
    const float bin_h = __fdiv_rn(h, (float)OUT_H);
    const float bin_w = __fdiv_rn(w, (float)OUT_W);
    const float gy = (float)oh + (sy ? 0.75f : 0.25f);
    const float gx = (float)ow + (sx ? 0.75f : 0.25f);
    const float yy = __fadd_rn(__fmul_rn(-h, 0.5f), __fmul_rn(gy, bin_h));
    const float xx = __fadd_rn(__fmul_rn(-w, 0.5f), __fmul_rn(gx, bin_w));
    const float x = __fadd_rn(__fsub_rn(__fmul_rn(xx, ct), __fmul_rn(yy, st)), cx);
    const float y = __fadd_rn(__fadd_rn(__fmul_rn(xx, st), __fmul_rn(yy, ct)), cy);

    const bool valid = (y >= -1.0f) && (y <= (float)Hl) &&
                       (x >= -1.0f) && (x <= (float)Hl);
    float yc = fminf(fmaxf(y, 0.0f), (float)(Hl - 1));
    float xc = fminf(fmaxf(x, 0.0f), (float)(Hl - 1));
    int y0 = (int)floorf(yc);
    int x0 = (int)floorf(xc);
    float ly = yc - (float)y0;
    float lx = xc - (float)x0;
    if (y0 >= Hl - 1) { y0 = Hl - 2; ly = 1.0f; }
    if (x0 >= Hl - 1) { x0 = Hl - 2; lx = 1.0f; }
    const float hy = 1.0f - ly, hx = 1.0f - lx;
    const float sc = valid ? 0.25f : 0.0f;  // fold 1/ns^2 sample mean

    s_desc[j] = make_uint4(
        (unsigned)((pixoff + (b * Hl + y0) * Hl + x0) * (NCH * 2)),  // byte off
        pk_rtn(sc * hy * hx, sc * hy * lx),
        pk_rtn(sc * ly * hx, sc * ly * lx), 0u);
  }
  __syncthreads();

  const int  wv   = threadIdx.x >> 6;
  const int  lane = threadIdx.x & 63;
  const char* ftb = (const char*)ft + ch2 * 256 + lane * 4;  // 2 channels / lane

  for (int ow = wv; ow < OUT_W; ow += 4) {
    h2_t m;
#pragma unroll
    for (int l = 0; l < 4; ++l) {
      const int rowb = 131072 >> l;  // (256>>l)*512 bytes

      // batch: 4 descriptor reads
      uint4 q0 = s_desc[ow * 16 + l * 4 + 0];
      uint4 q1 = s_desc[ow * 16 + l * 4 + 1];
      uint4 q2 = s_desc[ow * 16 + l * 4 + 2];
      uint4 q3 = s_desc[ow * 16 + l * 4 + 3];

      // batch: issue all 16 tap loads (16 VMEM in flight)
      unsigned tv[16];
      {
        const char* p0 = ftb + (int)q0.x;
        const char* p1 = ftb + (int)q1.x;
        const char* p2 = ftb + (int)q2.x;
        const char* p3 = ftb + (int)q3.x;
        tv[ 0] = *(const unsigned*)(p0);
        tv[ 1] = *(const unsigned*)(p0 + 512);
        tv[ 2] = *(const unsigned*)(p0 + rowb);
        tv[ 3] = *(const unsigned*)(p0 + rowb + 512);
        tv[ 4] = *(const unsigned*)(p1);
        tv[ 5] = *(const unsigned*)(p1 + 512);
        tv[ 6] = *(const unsigned*)(p1 + rowb);
        tv[ 7] = *(const unsigned*)(p1 + rowb + 512);
        tv[ 8] = *(const unsigned*)(p2);
        tv[ 9] = *(const unsigned*)(p2 + 512);
        tv[10] = *(const unsigned*)(p2 + rowb);
        tv[11] = *(const unsigned*)(p2 + rowb + 512);
        tv[12] = *(const unsigned*)(p3);
        tv[13] = *(const unsigned*)(p3 + 512);
        tv[14] = *(const unsigned*)(p3 + rowb);
        tv[15] = *(const unsigned*)(p3 + rowb + 512);
      }

      // 16 pk_fma in the exact reference accumulation order
      h2_t a = {(_Float16)0, (_Float16)0};
      {
        const h2_t w01 = as_h2(q0.y), w23 = as_h2(q0.z);
        a = __builtin_shufflevector(w01, w01, 0, 0) * as_h2(tv[ 0]) + a;
        a = __builtin_shufflevector(w01, w01, 1, 1) * as_h2(tv[ 1]) + a;
        a = __builtin_shufflevector(w23, w23, 0, 0) * as_h2(tv[ 2]) + a;
        a = __builtin_shufflevector(w23, w23, 1, 1) * as_h2(tv[ 3]) + a;
      }
      {
        const h2_t w01 = as_h2(q1.y), w23 = as_h2(q1.z);
        a = __builtin_shufflevector(w01, w01, 0, 0) * as_h2(tv[ 4]) + a;
        a = __builtin_shufflevector(w01, w01, 1, 1) * as_h2(tv[ 5]) + a;
        a = __builtin_shufflevector(w23, w23, 0, 0) * as_h2(tv[ 6]) + a;
        a = __builtin_shufflevector(w23, w23, 1, 1) * as_h2(tv[ 7]) + a;
      }
      {
        const h2_t w01 = as_h2(q2.y), w23 = as_h2(q2.z);
        a = __builtin_shufflevector(w01, w01, 0, 0) * as_h2(tv[ 8]) + a;
        a = __builtin_shufflevector(w01, w01, 1, 1) * as_h2(tv[ 9]) + a;
        a = __builtin_shufflevector(w23, w23, 0, 0) * as_h2(tv[10]) + a;
        a = __builtin_shufflevector(w23, w23, 1, 1) * as_h2(tv[11]) + a;
      }
      {
        const h2_t w01 = as_h2(q3.y), w23 = as_h2(q3.z);
        a = __builtin_shufflevector(w01, w01, 0, 0) * as_h2(tv[12]) + a;
        a = __builtin_shufflevector(w01, w01, 1, 1) * as_h2(tv[13]) + a;
        a = __builtin_shufflevector(w23, w23, 0, 0) * as_h2(tv[14]) + a;
        a = __builtin_shufflevector(w23, w23, 1, 1) * as_h2(tv[15]) + a;
      }

      if (l == 0) m = a;
      else        m = __builtin_elementwise_max(m, a);
    }
    s_out[ow * 66 + lane] = h2_bits(m);  // 2-way banks, free
  }
  __syncthreads();

  // ---- near-coalesced transposed write-out (f16 -> f32) ----
  // Plain stores: co-resident oh-blocks of the same roi merge partial 64 B
  // lines in L2 (NT stores here cost +48 MB write amplification, measured).
  const size_t outbase = (size_t)n * NCH * NBINS + (size_t)ch2 * 128 * NBINS +
                         (size_t)oh * OUT_W;
  const _Float16* sh = (const _Float16*)s_out;
#pragma unroll
  for (int j = 0; j < 18; ++j) {
    const int idx = threadIdx.x + j * 256;  // 0..4607, guard 4480
    if (idx < 128 * OUT_W) {
      const int cc = idx / OUT_W;           // magic-mul const div
      const int ww = idx - cc * OUT_W;
      out[outbase + (size_t)cc * NBINS + ww] = (float)sh[ww * 132 + cc];
    }
  }
}

// ---------------------------------------------------------------------------
extern "C" void kernel_launch(void* const* d_in, const int* in_sizes, int n_in,
                              void* d_out, int out_size, void* d_ws, size_t ws_size,
                              hipStream_t stream) {
  const float* f0 = (const float*)d_in[0];
  const float* f1 = (const float*)d_in[1];
  const float* f2 = (const float*)d_in[2];
  const float* f3 = (const float*)d_in[3];
  const float* rois = (const float*)d_in[4];
  ushort* ws = (ushort*)d_ws;
  float* out = (float*)d_out;

  transpose_all<<<10880, 256, 0, stream>>>(f0, f1, f2, f3, ws);
  roi_align_rotated_max<<<7168, 256, 0, stream>>>(ws, rois, out);
}